// Round 4
// baseline (138.986 us; speedup 1.0000x reference)
//
#include <hip/hip_runtime.h>
#include <cstdint>

#define NQ    8192
#define NNEG  16384
#define DIM   128
#define SPLIT 16
#define CHUNK (NNEG / SPLIT)          // 1024
// (1/TAU) * log2(e): MFMA output is directly the base-2 exponent
#define K_SCALE 7.2134752044448169f
#define LN2     0.69314718055994531f

typedef __attribute__((ext_vector_type(8))) int   i32x8;
typedef __attribute__((ext_vector_type(4))) float f32x4;

union U8 { i32x8 v; int4 h[2]; };

__device__ inline float waveReduceSum(float v) {
#pragma unroll
    for (int m = 32; m >= 1; m >>= 1) v += __shfl_xor(v, m, 64);
    return v;
}

// ---------------- kernel 1: f32 -> fp8 e4m3 convert + fused positive-logit dot ----
__global__ __launch_bounds__(256) void iw_prep(
    const float* __restrict__ q, const float* __restrict__ p,
    const float* __restrict__ neg,
    unsigned char* __restrict__ qb8, unsigned char* __restrict__ nb8,
    float* __restrict__ out)
{
    const int tid = threadIdx.x;
    const int t = blockIdx.x * 256 + tid;
    constexpr int QT = NQ * DIM / 8;      // 131072 q-threads
    if (t < QT) {
        const float4* q4 = (const float4*)q;
        float4 v0 = q4[t * 2], v1 = q4[t * 2 + 1];
        int w0 = __builtin_amdgcn_cvt_pk_fp8_f32(v0.x * K_SCALE, v0.y * K_SCALE, 0, false);
        w0     = __builtin_amdgcn_cvt_pk_fp8_f32(v0.z * K_SCALE, v0.w * K_SCALE, w0, true);
        int w1 = __builtin_amdgcn_cvt_pk_fp8_f32(v1.x * K_SCALE, v1.y * K_SCALE, 0, false);
        w1     = __builtin_amdgcn_cvt_pk_fp8_f32(v1.z * K_SCALE, v1.w * K_SCALE, w1, true);
        ((int2*)qb8)[t] = make_int2(w0, w1);
        // fused pos logit: q . pos (raw f32)
        const float4* p4 = (const float4*)p;
        float4 p0 = p4[t * 2], p1 = p4[t * 2 + 1];
        float acc = fmaf(v0.x, p0.x, fmaf(v0.y, p0.y, fmaf(v0.z, p0.z, v0.w * p0.w)));
        acc = fmaf(v1.x, p1.x, fmaf(v1.y, p1.y, fmaf(v1.z, p1.z, fmaf(v1.w, p1.w, acc))));
        acc = waveReduceSum(acc);
        __shared__ float red[4];
        if ((tid & 63) == 0) red[tid >> 6] = acc;
        __syncthreads();
        if (tid == 0) {
            float s = red[0] + red[1] + red[2] + red[3];
            atomicAdd(out, s * (-1.0f / (0.2f * (float)NQ)));
        }
    } else {
        int j = t - QT;                   // < 262144
        const float4* n4 = (const float4*)neg;
        float4 v0 = n4[j * 2], v1 = n4[j * 2 + 1];
        int w0 = __builtin_amdgcn_cvt_pk_fp8_f32(v0.x, v0.y, 0, false);
        w0     = __builtin_amdgcn_cvt_pk_fp8_f32(v0.z, v0.w, w0, true);
        int w1 = __builtin_amdgcn_cvt_pk_fp8_f32(v1.x, v1.y, 0, false);
        w1     = __builtin_amdgcn_cvt_pk_fp8_f32(v1.z, v1.w, w1, true);
        ((int2*)nb8)[j] = make_int2(w0, w1);
    }
}

// ---------------- kernel 2: flash-LSE main (MX-fp8 K=128, no LDS, no barriers) ----
// grid (64, 16): blockIdx.x = row block (BM=128), blockIdx.y = neg chunk (1024)
__global__ __launch_bounds__(256, 4) void iw_main(
    const unsigned char* __restrict__ qb8, const unsigned char* __restrict__ nb8,
    float2* __restrict__ partial)
{
    constexpr int BM = 128, BN = 64, NIT = CHUNK / BN;   // 16 iters
    const int tid  = threadIdx.x;
    const int lane = tid & 63;
    const int w    = tid >> 6;        // wave 0..3, owns 32 query rows; fully independent
    const int quad = lane >> 4;
    const int c0   = lane & 15;

    const int row0   = blockIdx.x * BM;
    const int nbase0 = blockIdx.y * CHUNK;

    // ---- A fragments from global (row-major fp8; lane holds k = quad*32..+32) ----
    U8 afrag[2];
#pragma unroll
    for (int rs = 0; rs < 2; ++rs) {
        const int qrow = row0 + w * 32 + rs * 16 + c0;
        const int4* pa = reinterpret_cast<const int4*>(qb8 + (size_t)qrow * DIM + quad * 32);
        afrag[rs].h[0] = pa[0];
        afrag[rs].h[1] = pa[1];
    }

    // ---- B base pointer: lane (quad,c0) reads neg row (nbase0 + ns*16 + c0),
    //      k-slice quad*32..+32. One wave instr = 16 dense rows (1 KB), L2-resident.
    const int4* bptr = reinterpret_cast<const int4*>(
        nb8 + (size_t)(nbase0 + c0) * DIM + quad * 32);
    // int4 strides: ns step = 16 rows * 128 B / 16 = 128; iter step = 64*128/16 = 512

    float m_s[2][4], l_s[2][4];
#pragma unroll
    for (int rs = 0; rs < 2; ++rs)
#pragma unroll
        for (int i = 0; i < 4; ++i) { m_s[rs][i] = -1e30f; l_s[rs][i] = 0.f; }

    const f32x4 zero4 = {0.f, 0.f, 0.f, 0.f};

    for (int it = 0; it < NIT; ++it) {
        const int4* pb = bptr + (size_t)it * 512;
        U8 b[4];
#pragma unroll
        for (int ns = 0; ns < 4; ++ns) {
            b[ns].h[0] = pb[ns * 128];
            b[ns].h[1] = pb[ns * 128 + 1];
        }

        f32x4 acc[2][4];
#pragma unroll
        for (int ns = 0; ns < 4; ++ns) {
            acc[0][ns] = __builtin_amdgcn_mfma_scale_f32_16x16x128_f8f6f4(
                afrag[0].v, b[ns].v, zero4, 0, 0, 0, 127, 0, 127);
            acc[1][ns] = __builtin_amdgcn_mfma_scale_f32_16x16x128_f8f6f4(
                afrag[1].v, b[ns].v, zero4, 0, 0, 0, 127, 0, 127);
        }

        // per-lane online logsumexp update (pure VALU; exp2-domain)
#pragma unroll
        for (int rs = 0; rs < 2; ++rs) {
#pragma unroll
            for (int i = 0; i < 4; ++i) {
                float y0 = acc[rs][0][i], y1 = acc[rs][1][i];
                float y2 = acc[rs][2][i], y3 = acc[rs][3][i];
                float m0 = m_s[rs][i];
                float nm = fmaxf(fmaxf(fmaxf(y0, y1), fmaxf(y2, y3)), m0);
                float t  = __builtin_amdgcn_exp2f(y0 - nm) + __builtin_amdgcn_exp2f(y1 - nm)
                         + __builtin_amdgcn_exp2f(y2 - nm) + __builtin_amdgcn_exp2f(y3 - nm);
                l_s[rs][i] = l_s[rs][i] * __builtin_amdgcn_exp2f(m0 - nm) + t;
                m_s[rs][i] = nm;
            }
        }
    }

    // ---- merge (m,l) across the 16 lanes of each quad-row group ----
#pragma unroll
    for (int rs = 0; rs < 2; ++rs) {
#pragma unroll
        for (int i = 0; i < 4; ++i) {
            float m = m_s[rs][i], l = l_s[rs][i];
#pragma unroll
            for (int s = 1; s < 16; s <<= 1) {
                float om = __shfl_xor(m, s, 64);
                float ol = __shfl_xor(l, s, 64);
                float nm = fmaxf(m, om);
                l = l * __builtin_amdgcn_exp2f(m - nm) + ol * __builtin_amdgcn_exp2f(om - nm);
                m = nm;
            }
            if (c0 == 0) {
                int grow = row0 + w * 32 + rs * 16 + quad * 4 + i;
                partial[(size_t)blockIdx.y * NQ + grow] = make_float2(m, l);
            }
        }
    }
}

// ---------------- kernel 3: merge chunks + mean reduce ----------------
__global__ __launch_bounds__(256) void iw_merge(
    const float2* __restrict__ partial, float* __restrict__ out)
{
    const int tid = threadIdx.x;
    const int row = blockIdx.x * 256 + tid;   // 32 blocks * 256 = 8192
    float M = -1e30f, L = 0.f;
#pragma unroll
    for (int c = 0; c < SPLIT; ++c) {
        float2 p = partial[(size_t)c * NQ + row];
        float nm = fmaxf(M, p.x);
        L = L * __builtin_amdgcn_exp2f(M - nm) + p.y * __builtin_amdgcn_exp2f(p.x - nm);
        M = nm;
    }
    float lse = LN2 * (M + __log2f(L));       // natural-log LSE of scores/tau
    float v = lse * (1.0f / (float)NQ);
    v = waveReduceSum(v);
    __shared__ float red[4];
    if ((tid & 63) == 0) red[tid >> 6] = v;
    __syncthreads();
    if (tid == 0) atomicAdd(out, red[0] + red[1] + red[2] + red[3]);
}

// ---------------- launch ----------------
extern "C" void kernel_launch(void* const* d_in, const int* in_sizes, int n_in,
                              void* d_out, int out_size, void* d_ws, size_t ws_size,
                              hipStream_t stream) {
    const float* q   = (const float*)d_in[0];
    const float* pos = (const float*)d_in[1];
    const float* neg = (const float*)d_in[2];
    float* out = (float*)d_out;

    unsigned char* qb8 = (unsigned char*)d_ws;                     // 1 MB
    unsigned char* nb8 = qb8 + (size_t)NQ * DIM;                   // 2 MB
    float2* partial    = (float2*)(nb8 + (size_t)NNEG * DIM);      // 1 MB

    hipMemsetAsync(out, 0, sizeof(float), stream);
    iw_prep <<<1536, 256, 0, stream>>>(q, pos, neg, qb8, nb8, out);
    iw_main <<<dim3(NQ / 128, SPLIT), 256, 0, stream>>>(qb8, nb8, partial);
    iw_merge<<<32,   256, 0, stream>>>(partial, out);
}

// Round 5
// 137.821 us; speedup vs baseline: 1.0085x; 1.0085x over previous
//
#include <hip/hip_runtime.h>
#include <cstdint>

#define NQ    8192
#define NNEG  16384
#define DIM   128
#define SPLIT 32
#define CHUNK (NNEG / SPLIT)          // 512
// (1/TAU) * log2(e): MFMA output is directly the base-2 exponent
#define K_SCALE 7.2134752044448169f
#define LN2     0.69314718055994531f

typedef __attribute__((ext_vector_type(8))) int   i32x8;
typedef __attribute__((ext_vector_type(4))) float f32x4;

union U8 { i32x8 v; int4 h[2]; };

// ---------------- kernel 1: f32 -> fp8 e4m3 convert + per-row pos-dot ----------------
// thread t < QT: 8 elems of q (row = t>>4); also q.pos partial, 16-lane-reduced
// thread t >= QT: 8 elems of neg
__global__ __launch_bounds__(256) void iw_prep(
    const float* __restrict__ q, const float* __restrict__ p,
    const float* __restrict__ neg,
    unsigned char* __restrict__ qb8, unsigned char* __restrict__ nb8,
    float* __restrict__ posdot, float* __restrict__ out)
{
    const int t = blockIdx.x * 256 + threadIdx.x;
    constexpr int QT = NQ * DIM / 8;      // 131072 q-threads (512 blocks)
    if (t < QT) {
        if (t == 0) out[0] = 0.f;
        const float4* q4 = (const float4*)q;
        float4 v0 = q4[t * 2], v1 = q4[t * 2 + 1];
        int w0 = __builtin_amdgcn_cvt_pk_fp8_f32(v0.x * K_SCALE, v0.y * K_SCALE, 0, false);
        w0     = __builtin_amdgcn_cvt_pk_fp8_f32(v0.z * K_SCALE, v0.w * K_SCALE, w0, true);
        int w1 = __builtin_amdgcn_cvt_pk_fp8_f32(v1.x * K_SCALE, v1.y * K_SCALE, 0, false);
        w1     = __builtin_amdgcn_cvt_pk_fp8_f32(v1.z * K_SCALE, v1.w * K_SCALE, w1, true);
        ((int2*)qb8)[t] = make_int2(w0, w1);
        // raw q.pos partial (8 elems)
        const float4* p4 = (const float4*)p;
        float4 p0 = p4[t * 2], p1 = p4[t * 2 + 1];
        float d = fmaf(v0.x, p0.x, fmaf(v0.y, p0.y, fmaf(v0.z, p0.z, v0.w * p0.w)));
        d = fmaf(v1.x, p1.x, fmaf(v1.y, p1.y, fmaf(v1.z, p1.z, fmaf(v1.w, p1.w, d))));
        // reduce across the 16 lanes covering one row (no atomics)
#pragma unroll
        for (int s = 1; s < 16; s <<= 1) d += __shfl_xor(d, s, 64);
        if ((threadIdx.x & 15) == 0) posdot[t >> 4] = d;
    } else {
        int j = t - QT;                   // < 262144
        const float4* n4 = (const float4*)neg;
        float4 v0 = n4[j * 2], v1 = n4[j * 2 + 1];
        int w0 = __builtin_amdgcn_cvt_pk_fp8_f32(v0.x, v0.y, 0, false);
        w0     = __builtin_amdgcn_cvt_pk_fp8_f32(v0.z, v0.w, w0, true);
        int w1 = __builtin_amdgcn_cvt_pk_fp8_f32(v1.x, v1.y, 0, false);
        w1     = __builtin_amdgcn_cvt_pk_fp8_f32(v1.z, v1.w, w1, true);
        ((int2*)nb8)[j] = make_int2(w0, w1);
    }
}

// ---------------- kernel 2: flash-LSE main (MX-fp8 K=128, no LDS, reg-pipelined) ----
// grid (64, 32): blockIdx.x = row block (BM=128), blockIdx.y = neg chunk (512)
__global__ __launch_bounds__(256, 3) void iw_main(
    const unsigned char* __restrict__ qb8, const unsigned char* __restrict__ nb8,
    float2* __restrict__ partial)
{
    constexpr int BM = 128, BN = 64, NIT = CHUNK / BN;   // 8 iters
    const int tid  = threadIdx.x;
    const int lane = tid & 63;
    const int w    = tid >> 6;        // wave 0..3, owns 32 query rows; fully independent
    const int quad = lane >> 4;
    const int c0   = lane & 15;

    const int row0   = blockIdx.x * BM;
    const int nbase0 = blockIdx.y * CHUNK;

    // ---- A fragments from global (row-major fp8; lane holds k = quad*32..+32) ----
    U8 afrag[2];
#pragma unroll
    for (int rs = 0; rs < 2; ++rs) {
        const int qrow = row0 + w * 32 + rs * 16 + c0;
        const int4* pa = reinterpret_cast<const int4*>(qb8 + (size_t)qrow * DIM + quad * 32);
        afrag[rs].h[0] = pa[0];
        afrag[rs].h[1] = pa[1];
    }

    // ---- B base: lane (quad,c0) reads neg row (nbase0 + ns*16 + c0), k = quad*32..+32
    const int4* bptr = reinterpret_cast<const int4*>(
        nb8 + (size_t)(nbase0 + c0) * DIM + quad * 32);
    // int4 strides: ns step = 128; iter step = 512

    float m_s[2][4], l_s[2][4];
#pragma unroll
    for (int rs = 0; rs < 2; ++rs)
#pragma unroll
        for (int i = 0; i < 4; ++i) { m_s[rs][i] = -1e30f; l_s[rs][i] = 0.f; }

    const f32x4 zero4 = {0.f, 0.f, 0.f, 0.f};

    // ---- prologue: load B tile for iter 0 into registers ----
    int4 bc[8];
#pragma unroll
    for (int ns = 0; ns < 4; ++ns) {
        bc[2 * ns]     = bptr[ns * 128];
        bc[2 * ns + 1] = bptr[ns * 128 + 1];
    }

#pragma unroll 2
    for (int it = 0; it < NIT; ++it) {
        // issue next tile's loads FIRST (independent; hidden behind MFMA+softmax)
        int4 bn[8];
        const int itn = (it + 1 < NIT) ? (it + 1) : 0;   // wrap to stay in-bounds
        const int4* pbn = bptr + (size_t)itn * 512;
#pragma unroll
        for (int ns = 0; ns < 4; ++ns) {
            bn[2 * ns]     = pbn[ns * 128];
            bn[2 * ns + 1] = pbn[ns * 128 + 1];
        }

        f32x4 acc[2][4];
#pragma unroll
        for (int ns = 0; ns < 4; ++ns) {
            U8 b;
            b.h[0] = bc[2 * ns];
            b.h[1] = bc[2 * ns + 1];
            acc[0][ns] = __builtin_amdgcn_mfma_scale_f32_16x16x128_f8f6f4(
                afrag[0].v, b.v, zero4, 0, 0, 0, 127, 0, 127);
            acc[1][ns] = __builtin_amdgcn_mfma_scale_f32_16x16x128_f8f6f4(
                afrag[1].v, b.v, zero4, 0, 0, 0, 127, 0, 127);
        }

        // per-lane online logsumexp update (pure VALU; exp2-domain)
#pragma unroll
        for (int rs = 0; rs < 2; ++rs) {
#pragma unroll
            for (int i = 0; i < 4; ++i) {
                float y0 = acc[rs][0][i], y1 = acc[rs][1][i];
                float y2 = acc[rs][2][i], y3 = acc[rs][3][i];
                float m0 = m_s[rs][i];
                float nm = fmaxf(fmaxf(fmaxf(y0, y1), fmaxf(y2, y3)), m0);
                float t  = __builtin_amdgcn_exp2f(y0 - nm) + __builtin_amdgcn_exp2f(y1 - nm)
                         + __builtin_amdgcn_exp2f(y2 - nm) + __builtin_amdgcn_exp2f(y3 - nm);
                l_s[rs][i] = l_s[rs][i] * __builtin_amdgcn_exp2f(m0 - nm) + t;
                m_s[rs][i] = nm;
            }
        }

        // rotate double buffer (renamed by regalloc)
#pragma unroll
        for (int j = 0; j < 8; ++j) bc[j] = bn[j];
    }

    // ---- merge (m,l) across the 16 lanes of each quad-row group ----
#pragma unroll
    for (int rs = 0; rs < 2; ++rs) {
#pragma unroll
        for (int i = 0; i < 4; ++i) {
            float m = m_s[rs][i], l = l_s[rs][i];
#pragma unroll
            for (int s = 1; s < 16; s <<= 1) {
                float om = __shfl_xor(m, s, 64);
                float ol = __shfl_xor(l, s, 64);
                float nm = fmaxf(m, om);
                l = l * __builtin_amdgcn_exp2f(m - nm) + ol * __builtin_amdgcn_exp2f(om - nm);
                m = nm;
            }
            if (c0 == 0) {
                int grow = row0 + w * 32 + rs * 16 + quad * 4 + i;
                partial[(size_t)blockIdx.y * NQ + grow] = make_float2(m, l);
            }
        }
    }
}

// ---------------- kernel 3: merge chunks + pos logit + mean reduce ----------------
__global__ __launch_bounds__(256) void iw_merge(
    const float2* __restrict__ partial, const float* __restrict__ posdot,
    float* __restrict__ out)
{
    const int tid = threadIdx.x;
    const int row = blockIdx.x * 256 + tid;   // 32 blocks * 256 = 8192
    float M = -1e30f, L = 0.f;
#pragma unroll
    for (int c = 0; c < SPLIT; ++c) {
        float2 p = partial[(size_t)c * NQ + row];
        float nm = fmaxf(M, p.x);
        L = L * __builtin_amdgcn_exp2f(M - nm) + p.y * __builtin_amdgcn_exp2f(p.x - nm);
        M = nm;
    }
    float lse = LN2 * (M + __log2f(L));       // natural-log LSE of scores/tau
    float v = (lse - 5.0f * posdot[row]) * (1.0f / (float)NQ);
#pragma unroll
    for (int s = 32; s >= 1; s >>= 1) v += __shfl_xor(v, s, 64);
    __shared__ float red[4];
    if ((tid & 63) == 0) red[tid >> 6] = v;
    __syncthreads();
    if (tid == 0) atomicAdd(out, red[0] + red[1] + red[2] + red[3]);
}

// ---------------- launch ----------------
extern "C" void kernel_launch(void* const* d_in, const int* in_sizes, int n_in,
                              void* d_out, int out_size, void* d_ws, size_t ws_size,
                              hipStream_t stream) {
    const float* q   = (const float*)d_in[0];
    const float* pos = (const float*)d_in[1];
    const float* neg = (const float*)d_in[2];
    float* out = (float*)d_out;

    unsigned char* qb8 = (unsigned char*)d_ws;                     // 1 MB
    unsigned char* nb8 = qb8 + (size_t)NQ * DIM;                   // 2 MB
    float2* partial    = (float2*)(nb8 + (size_t)NNEG * DIM);      // 2 MB
    float* posdot      = (float*)(partial + (size_t)SPLIT * NQ);   // 32 KB

    iw_prep <<<1536, 256, 0, stream>>>(q, pos, neg, qb8, nb8, posdot, out);
    iw_main <<<dim3(NQ / 128, SPLIT), 256, 0, stream>>>(qb8, nb8, partial);
    iw_merge<<<32,   256, 0, stream>>>(partial, posdot, out);
}